// Round 6
// baseline (2480.945 us; speedup 1.0000x reference)
//
#include <hip/hip_runtime.h>
#include <math.h>

#define M_ROWS 2048
#define N_COLS 2048
#define DIMS 512
#define IN_STRIDE 513

constexpr float GAMMA = 0.001f;
constexpr float LOG2E = 1.44269504088896f;
constexpr float LN2   = 0.69314718055995f;

// hardware base-2 exp/log (v_exp_f32 / v_log_f32). NOTE: __exp2f/__log2f collide
// with glibc math.h internals on this toolchain — use the amdgcn builtins.
__device__ __forceinline__ float fexp2(float x) { return __builtin_amdgcn_exp2f(x); }
__device__ __forceinline__ float flog2(float x) { return __builtin_amdgcn_logf(x); }

// ---------------- argsort by timestamp (last column), stable ----------------
__global__ void argsort_kernel(const float* __restrict__ a, const float* __restrict__ b,
                               int* __restrict__ permA, int* __restrict__ permB) {
    const float* src = blockIdx.y ? b : a;
    int* perm = blockIdx.y ? permB : permA;
    __shared__ float keys[M_ROWS];
    for (int j = threadIdx.x; j < M_ROWS; j += blockDim.x)
        keys[j] = src[(size_t)j * IN_STRIDE + DIMS];
    __syncthreads();
    int i = blockIdx.x * blockDim.x + threadIdx.x;
    float ki = keys[i];
    int rank = 0;
    for (int j = 0; j < M_ROWS; ++j) {
        float kj = keys[j];
        rank += (kj < ki) || (kj == ki && j < i);  // stable rank
    }
    perm[rank] = i;
}

// ---------------- gather sorted rows + L2-normalize (drop time col) ----------------
__global__ __launch_bounds__(128) void norm_kernel(const float* __restrict__ a, const float* __restrict__ b,
                                                   const int* __restrict__ permA, const int* __restrict__ permB,
                                                   float* __restrict__ Ahat, float* __restrict__ Bhat) {
    const float* src = blockIdx.y ? b : a;
    const int* perm = blockIdx.y ? permB : permA;
    float* dst = blockIdx.y ? Bhat : Ahat;
    int r = blockIdx.x;
    int row = perm[r];
    const float* p = src + (size_t)row * IN_STRIDE;
    int tid = threadIdx.x;
    float v0 = p[tid], v1 = p[tid + 128], v2 = p[tid + 256], v3 = p[tid + 384];
    float ss = v0 * v0 + v1 * v1 + v2 * v2 + v3 * v3;
    #pragma unroll
    for (int off = 32; off > 0; off >>= 1) ss += __shfl_down(ss, off);
    __shared__ float red[2];
    if ((tid & 63) == 0) red[tid >> 6] = ss;
    __syncthreads();
    float inv = 1.0f / sqrtf(red[0] + red[1] + 1e-10f);
    float* q = dst + (size_t)r * DIMS;
    q[tid] = v0 * inv; q[tid + 128] = v1 * inv; q[tid + 256] = v2 * inv; q[tid + 384] = v3 * inv;
}

// ---------------- GEMM: Q[i][n] = exp(-1 - dot(Ahat[i], Bhat[n])) = exp(cost-2) ----------------
__global__ __launch_bounds__(256) void gemm_kernel(const float* __restrict__ A, const float* __restrict__ B,
                                                   float* __restrict__ Q) {
    __shared__ float As[16][68];
    __shared__ float Bs[16][68];
    int tid = threadIdx.x;
    int tx = tid & 15, ty = tid >> 4;
    int row0 = blockIdx.y * 64;
    int col0 = blockIdx.x * 64;
    int lrow = tid >> 2;          // 0..63
    int lk = (tid & 3) * 4;       // 0,4,8,12
    const float* ap = A + (size_t)(row0 + lrow) * DIMS + lk;
    const float* bp = B + (size_t)(col0 + lrow) * DIMS + lk;
    float acc[4][4] = {};
    for (int k0 = 0; k0 < DIMS; k0 += 16) {
        float4 av = *(const float4*)ap; ap += 16;
        float4 bv = *(const float4*)bp; bp += 16;
        __syncthreads();
        As[lk + 0][lrow] = av.x; As[lk + 1][lrow] = av.y; As[lk + 2][lrow] = av.z; As[lk + 3][lrow] = av.w;
        Bs[lk + 0][lrow] = bv.x; Bs[lk + 1][lrow] = bv.y; Bs[lk + 2][lrow] = bv.z; Bs[lk + 3][lrow] = bv.w;
        __syncthreads();
        #pragma unroll
        for (int k = 0; k < 16; ++k) {
            float4 a4 = *(const float4*)&As[k][ty * 4];
            float4 b4 = *(const float4*)&Bs[k][tx * 4];
            float aa[4] = {a4.x, a4.y, a4.z, a4.w};
            float bb[4] = {b4.x, b4.y, b4.z, b4.w};
            #pragma unroll
            for (int u = 0; u < 4; ++u)
                #pragma unroll
                for (int v = 0; v < 4; ++v)
                    acc[u][v] += aa[u] * bb[v];
        }
    }
    #pragma unroll
    for (int u = 0; u < 4; ++u) {
        float4 o;
        o.x = __expf(-1.0f - acc[u][0]);
        o.y = __expf(-1.0f - acc[u][1]);
        o.z = __expf(-1.0f - acc[u][2]);
        o.w = __expf(-1.0f - acc[u][3]);
        *(float4*)&Q[(size_t)(row0 + ty * 4 + u) * N_COLS + col0 + tx * 4] = o;
    }
}

// ---------------- per-row softmax denom -> rs2 = log2e/(gamma*denom) ----------------
// log2 We = -rs2 ; log2 Wo[n] = -rs2*Q[n]
__global__ __launch_bounds__(256) void rowstat_kernel(const float* __restrict__ Q,
                                                      float* __restrict__ rowscale) {
    int i = blockIdx.x;
    const float* q = Q + (size_t)i * N_COLS;
    int tid = threadIdx.x;
    float4 x = *(const float4*)(q + tid * 4);
    float4 y = *(const float4*)(q + 1024 + tid * 4);
    float s = x.x + x.y + x.z + x.w + y.x + y.y + y.z + y.w;
    #pragma unroll
    for (int off = 32; off > 0; off >>= 1) s += __shfl_down(s, off);
    __shared__ float red[4];
    if ((tid & 63) == 0) red[tid >> 6] = s;
    __syncthreads();
    if (tid == 0) {
        float denom = 2049.0f + red[0] + red[1] + red[2] + red[3];
        rowscale[i] = (LOG2E / GAMMA) / denom;
    }
}

// ---------------- LG2[i][n] = log2(We_i + Wo_i[n]) in place over Q ----------------
__device__ __forceinline__ float lse2pair(float a, float b) {
    float M = fmaxf(a, b);
    return M + flog2(fexp2(a - M) + fexp2(b - M));
}
__global__ __launch_bounds__(256) void lg_kernel(float* __restrict__ Q, const float* __restrict__ rowscale) {
    int e = blockIdx.x * blockDim.x + threadIdx.x;   // float4 index
    float rs2 = rowscale[e >> 9];
    float a = -rs2;                                   // log2 We
    float4 x = *(float4*)(Q + (size_t)e * 4);
    x.x = lse2pair(a, -rs2 * x.x);
    x.y = lse2pair(a, -rs2 * x.y);
    x.z = lse2pair(a, -rs2 * x.z);
    x.w = lse2pair(a, -rs2 * x.w);
    *(float4*)(Q + (size_t)e * 4) = x;
}

// ---------------- (m,s) pair arithmetic: value = m + log2(s) ----------------
struct Pair { float m, s; };

// combine two pairs (log-sum-exp in base 2); one transcendental, no log
__device__ __forceinline__ Pair pcomb(Pair a, Pair b) {
    float e = fexp2(-fabsf(a.m - b.m));
    bool c = a.m >= b.m;
    Pair r;
    r.m = c ? a.m : b.m;
    r.s = c ? fmaf(b.s, e, a.s) : fmaf(a.s, e, b.s);
    return r;
}
// exact renormalization: pull s's exponent into m (s -> [1,2)), integer ops only
__device__ __forceinline__ void renorm(float& m, float& s) {
    int bits = __float_as_int(s);
    int ex = ((bits >> 23) & 255) - 127;
    m += (float)ex;
    s = __int_as_float(bits - (ex << 23));
}

// ---------------- sequential DP, even-column fold, log2 domain, PAIR STATE ----------------
// P[n] kept as (m,s): value = log2 of prefix-sum of prev E-row through even col 2n.
// Per row i:  g[m] = LG2_i[m] + P_old[m]   (pair: m += LG2, s unchanged)
//             P_new[n] = LSE(excl-prefix(g)[n], lwe + P_old[n])
//             h_new    = LSE(total(g), lwe + h_old)          [wave 7]
// No log2 in the loop; s renormalized into [1,2) by exponent extraction.
// Prefetch: 2-buffer pipeline, load issued AFTER the barrier so it has a full
// inter-barrier interval in flight before the next barrier's vmcnt(0) drain.
__global__ __launch_bounds__(512) void dp_kernel(const float* __restrict__ LG2,
                                                 const float* __restrict__ Rs,
                                                 float* __restrict__ out) {
    const int tid = threadIdx.x;
    const int lane = tid & 63;
    const int wid = tid >> 6;        // 0..7
    __shared__ float2 wtot[2][8];
    __shared__ float sRs[M_ROWS];
    for (int k = tid; k < M_ROWS; k += 512) sRs[k] = Rs[k];
    __syncthreads();

    float mP0 = 0.f, sP0 = 1.f, mP1 = 0.f, sP1 = 1.f;
    float mP2 = 0.f, sP2 = 1.f, mP3 = 0.f, sP3 = 1.f;
    float mH = 0.f, sH = 1.f;

    float4 cur = *(const float4*)(LG2 + 4 * tid);                      // row 0
    float4 nxt = *(const float4*)(LG2 + (size_t)N_COLS + 4 * tid);     // row 1

    for (int i = 0; i < M_ROWS; ++i) {
        float lwe = -sRs[i];
        float4 cw = cur;

        // g pairs (old P, m shifted by log-weight)
        Pair ga{cw.x + mP0, sP0}, gb{cw.y + mP1, sP1};
        Pair gc{cw.z + mP2, sP2}, gd{cw.w + mP3, sP3};
        // local tree (depth 2)
        Pair g01 = pcomb(ga, gb);
        Pair g23 = pcomb(gc, gd);
        Pair q   = pcomb(g01, g23);

        // warp inclusive scan on pairs (6 steps)
        Pair v = q;
        #pragma unroll
        for (int off = 1; off < 64; off <<= 1) {
            float pm = __shfl_up(v.m, off);
            float ps = __shfl_up(v.s, off);
            if (lane >= off) v = pcomb(v, Pair{pm, ps});
        }
        // lane-exclusive prefix
        float em = __shfl_up(v.m, 1), es = __shfl_up(v.s, 1);
        if (lane == 0) { em = -1e30f; es = 0.f; }
        if (lane == 63) wtot[i & 1][wid] = make_float2(v.m, v.s);
        __syncthreads();

        // rotate prefetch buffers; issue next load AFTER the barrier
        cur = nxt;
        if (i + 2 < M_ROWS) nxt = *(const float4*)(LG2 + (size_t)(i + 2) * N_COLS + 4 * tid);

        // wave-total tree fold (all lanes redundantly; depth <= 4)
        const float2* wt = wtot[i & 1];
        Pair w0{wt[0].x, wt[0].y}, w1{wt[1].x, wt[1].y}, w2{wt[2].x, wt[2].y}, w3{wt[3].x, wt[3].y};
        Pair w4{wt[4].x, wt[4].y}, w5{wt[5].x, wt[5].y}, w6{wt[6].x, wt[6].y}, w7{wt[7].x, wt[7].y};
        Pair c01 = pcomb(w0, w1), c23 = pcomb(w2, w3), c45 = pcomb(w4, w5);
        Pair c0123 = pcomb(c01, c23);
        // wave-exclusive prefix via binary decomposition of wid (wave-uniform branches)
        Pair wex{-1e30f, 0.f};
        if (wid & 4) wex = c0123;
        if (wid & 2) wex = pcomb(wex, (wid & 4) ? c45 : c01);
        if (wid & 1) wex = pcomb(wex, (wid == 1) ? w0 : (wid == 3) ? w2 : (wid == 5) ? w4 : w6);
        // base = exclusive prefix through column 4t-1
        Pair base = pcomb(wex, Pair{em, es});

        // bases for the 4 columns (independent after depth-2 chain)
        Pair b1 = pcomb(base, ga);
        Pair b2 = pcomb(base, g01);
        Pair b3 = pcomb(b2, gc);

        // P updates (independent pair combines)
        Pair n0 = pcomb(base, Pair{mP0 + lwe, sP0});
        Pair n1 = pcomb(b1,   Pair{mP1 + lwe, sP1});
        Pair n2 = pcomb(b2,   Pair{mP2 + lwe, sP2});
        Pair n3 = pcomb(b3,   Pair{mP3 + lwe, sP3});

        // h: wave 7 folds the full row total
        if (wid == 7) {
            Pair c67 = pcomb(w6, w7);
            Pair tot = pcomb(pcomb(c0123, c45), c67);
            Pair hh = pcomb(tot, Pair{mH + lwe, sH});
            mH = hh.m; sH = hh.s;
            renorm(mH, sH);
        }

        mP0 = n0.m; sP0 = n0.s; renorm(mP0, sP0);
        mP1 = n1.m; sP1 = n1.s; renorm(mP1, sP1);
        mP2 = n2.m; sP2 = n2.s; renorm(mP2, sP2);
        mP3 = n3.m; sP3 = n3.s; renorm(mP3, sP3);
    }
    if (tid == 511) out[0] = -GAMMA * LN2 * (mH + flog2(sH));
}

extern "C" void kernel_launch(void* const* d_in, const int* in_sizes, int n_in,
                              void* d_out, int out_size, void* d_ws, size_t ws_size,
                              hipStream_t stream) {
    (void)in_sizes; (void)n_in; (void)out_size; (void)ws_size;
    const float* a = (const float*)d_in[0];
    const float* b = (const float*)d_in[1];
    float* out = (float*)d_out;
    char* ws = (char*)d_ws;
    float* Q        = (float*)(ws);                                    // 16 MB (Q, then LG2 in place)
    float* Ahat     = (float*)(ws + (size_t)16 * 1024 * 1024);         // 4 MB
    float* Bhat     = (float*)(ws + (size_t)20 * 1024 * 1024);         // 4 MB
    float* rowscale = (float*)(ws + (size_t)24 * 1024 * 1024);         // 8 KB
    int* permA      = (int*)(ws + (size_t)24 * 1024 * 1024 + 8192);    // 8 KB
    int* permB      = (int*)(ws + (size_t)24 * 1024 * 1024 + 16384);   // 8 KB

    argsort_kernel<<<dim3(8, 2), 256, 0, stream>>>(a, b, permA, permB);
    norm_kernel<<<dim3(2048, 2), 128, 0, stream>>>(a, b, permA, permB, Ahat, Bhat);
    gemm_kernel<<<dim3(32, 32), 256, 0, stream>>>(Ahat, Bhat, Q);
    rowstat_kernel<<<2048, 256, 0, stream>>>(Q, rowscale);
    lg_kernel<<<4096, 256, 0, stream>>>(Q, rowscale);
    dp_kernel<<<1, 512, 0, stream>>>(Q, rowscale, out);
}